// Round 5
// baseline (162.356 us; speedup 1.0000x reference)
//
#include <hip/hip_runtime.h>
#include <hip/hip_bf16.h>

#define DEVI __device__ __forceinline__

constexpr int B_ = 32, CI = 128, CM = 256, H_ = 32, W_ = 32;
constexpr int S_ = 1024, NB = 100;
constexpr float LAMF = 0.7f, ILAMF = 0.3f, SCALEF = 3.0f;
// chunked channel-last layouts: [b][ch/8][pos][8ch]
constexpr size_t XSZ = (size_t)32 * 16 * 1156 * 8;   // per-ab xpad elems (34x34 pos)
constexpr size_t XBS = (size_t)16 * 1156 * 8;        // per-b stride
constexpr size_t CSZ = (size_t)32 * 32 * 324 * 8;    // per-ab cpad elems (18x18 pos)
constexpr size_t CBS = (size_t)32 * 324 * 8;

typedef short bf8 __attribute__((ext_vector_type(8)));
typedef float f4 __attribute__((ext_vector_type(4)));
typedef unsigned short u16;
typedef unsigned int u32;

struct alignas(8) us4 { u16 v[4]; };
struct alignas(16) us8 { u16 v[8]; };

// deconv K-chunk tap order, parity-grouped: par0{0,2,6,8} par1{1,7} par2{3,5} par3{4}
__device__ const int TAPD9[9] = {0, 2, 6, 8, 1, 7, 3, 5, 4};

DEVI u16 f2bf(float f) {
    unsigned u = __builtin_bit_cast(unsigned, f);
    u += 0x7FFFu + ((u >> 16) & 1u);
    return (u16)(u >> 16);
}
DEVI float bf2f(u16 h) {
    unsigned u = ((unsigned)h) << 16;
    return __builtin_bit_cast(float, u);
}

DEVI void gll16(const void* g, void* l) {
    __builtin_amdgcn_global_load_lds(
        (const __attribute__((address_space(1))) u32*)g,
        (__attribute__((address_space(3))) u32*)l, 16, 0, 0);
}

DEVI float waveSum(float v) {
#pragma unroll
    for (int off = 32; off > 0; off >>= 1) v += __shfl_down(v, off, 64);
    return v;
}
DEVI float blockSum256(float v, float* lds4) {
    v = waveSum(v);
    int wid = threadIdx.x >> 6, lane = threadIdx.x & 63;
    __syncthreads();
    if (lane == 0) lds4[wid] = v;
    __syncthreads();
    return lds4[0] + lds4[1] + lds4[2] + lds4[3];
}
DEVI float blockSum128(float v, float* lds2) {
    v = waveSum(v);
    int wid = threadIdx.x >> 6, lane = threadIdx.x & 63;
    __syncthreads();
    if (lane == 0) lds2[wid] = v;
    __syncthreads();
    return lds2[0] + lds2[1];
}
DEVI float blockMax128(float v, float* lds2) {
#pragma unroll
    for (int off = 32; off > 0; off >>= 1) v = fmaxf(v, __shfl_down(v, off, 64));
    int wid = threadIdx.x >> 6, lane = threadIdx.x & 63;
    __syncthreads();
    if (lane == 0) lds2[wid] = v;
    __syncthreads();
    return fmaxf(lds2[0], lds2[1]);
}

// ---- weight prep: staging-linear, fragment-ordered, PRE-SWIZZLED layouts ----
// A1p: [Mt2][kc36][slot512][8]  slot t: m=t>>2 (0..127), s4=t&3, k8=s4^(m&3)
//      oc = Mt*128+m, ch = (kc&3)*32 + k8*8 + e, tap = kc>>2
// A2p/A3p: [kc72][slot512][8]   m=oc(0..127), ch=(kc&7)*32+k8*8+e, tap=kc>>3 (A3p: TAPD9)
__global__ __launch_bounds__(256) void k_prep_w(const float* __restrict__ We,
                                                const float* __restrict__ Wf,
                                                const float* __restrict__ Wd,
                                                u16* __restrict__ A1p,
                                                u16* __restrict__ A2p,
                                                u16* __restrict__ A3p) {
    int i = blockIdx.x * 256 + threadIdx.x;  // 294912
    {
        int e = i & 7, tt = (i >> 3) & 511, j = i >> 12;  // j 0..71
        int Mt = j / 36, kc = j - Mt * 36;
        int m = tt >> 2, s4 = tt & 3, k8 = s4 ^ (m & 3);
        int tap = kc >> 2, q = kc & 3;
        int ch = q * 32 + k8 * 8 + e;
        int oc = Mt * 128 + m;
        A1p[i] = f2bf(We[((size_t)oc * CI + ch) * 9 + tap]);
    }
    {
        int e = i & 7, tt = (i >> 3) & 511, kc = i >> 12;  // 0..71
        int m = tt >> 2, s4 = tt & 3, k8 = s4 ^ (m & 3);
        int q = kc & 7;
        int ch = q * 32 + k8 * 8 + e;
        A2p[i] = f2bf(Wf[((size_t)m * CM + ch) * 9 + (kc >> 3)]);
        A3p[i] = f2bf(Wd[((size_t)m * CM + ch) * 9 + TAPD9[kc >> 3]]);
    }
}

// ---- proxies ----
__global__ __launch_bounds__(128) void k_prox(const float* __restrict__ P,
                                              float* __restrict__ PnT,
                                              float* __restrict__ pn2) {
    __shared__ float lds2[2];
    int k = blockIdx.x, t = threadIdx.x;
    float v = P[k * CI + t];
    float ss = blockSum128(v * v, lds2);
    float sc = SCALEF / fmaxf(sqrtf(ss), 1e-12f);
    float pv = v * sc;
    PnT[t * NB + k] = pv;
    float s2 = blockSum128(pv * pv, lds2);
    if (t == 0) pn2[k] = s2;
}

// ---- zero the padding rings of xpad and cpad (replaces 30MB of memsets) ----
__global__ __launch_bounds__(256) void k_ring(u16* __restrict__ xpad, u16* __restrict__ cpad) {
    int b = blockIdx.x, ab = blockIdx.y, t = threadIdx.x;
    u16* xp = xpad + (size_t)ab * XSZ + (size_t)b * XBS;
    u16* cp = cpad + (size_t)ab * CSZ + (size_t)b * CBS;
    us8 z = {};
    for (int i = t; i < 132 * 16; i += 256) {
        int cc = i / 132, rp = i - cc * 132;
        int pos;
        if (rp < 68) pos = (rp < 34) ? (32 * 34 + rp) : (33 * 34 + rp - 34);
        else { int r2 = rp - 68; pos = (r2 >> 1) * 34 + 32 + (r2 & 1); }
        *(us8*)(xp + ((size_t)cc * 1156 + pos) * 8) = z;
    }
    for (int i = t; i < 68 * 32; i += 256) {
        int cc = i / 68, rp = i - cc * 68;
        int pos;
        if (rp < 36) pos = (rp < 18) ? rp : (17 * 18 + rp - 18);
        else { int r2 = rp - 36; pos = (1 + (r2 >> 1)) * 18 + ((r2 & 1) ? 17 : 0); }
        *(us8*)(cp + ((size_t)cc * 324 + pos) * 8) = z;
    }
}

// ---- fused: x -> bf16 chunked xpad + invd (LDS-only) + meanx/meanfl ----
__global__ __launch_bounds__(256) void k_xpose(const float* __restrict__ xa,
                                               const float* __restrict__ xb,
                                               u16* __restrict__ xpad,
                                               float* __restrict__ meanbuf) {
    __shared__ float ldsx[128][64];   // 32KB
    __shared__ float sred[256];
    __shared__ float sinv[64];
    int b = blockIdx.x, yg = blockIdx.y, ab = blockIdx.z;
    int t = threadIdx.x;
    const float* x = (ab ? xb : xa) + (size_t)b * CI * S_ + yg * 64;
    int c4 = t >> 6, p = t & 63;
    for (int c0 = 0; c0 < 32; ++c0) {
        int c = c0 * 4 + c4;
        ldsx[c][p] = x[(size_t)c * S_ + p];
    }
    __syncthreads();
    int qc = t >> 6;
    int y = yg * 2 + (p >> 5), xcol = p & 31;
    u16* ox = xpad + (size_t)ab * XSZ + (size_t)b * XBS;
    float ss = 0.f;
#pragma unroll
    for (int c8 = 0; c8 < 4; ++c8) {
        int cb = qc * 32 + c8 * 8;
        int cc = cb >> 3;
        us8 pk;
#pragma unroll
        for (int j = 0; j < 8; ++j) {
            float v = ldsx[cb + j][p];
            ss = fmaf(v, v, ss);
            pk.v[j] = f2bf(v);
        }
        *(us8*)(ox + ((size_t)cc * 1156 + y * 34 + xcol) * 8) = pk;
    }
    sred[t] = ss;
    __syncthreads();
    if (t < 64) {
        float s = sred[t] + sred[t + 64] + sred[t + 128] + sred[t + 192];
        sinv[t] = 1.f / fmaxf(sqrtf(s), 1e-12f);
    }
    __syncthreads();
    int c = t >> 1, h = t & 1;
    float sx = 0.f, sf = 0.f;
    for (int i = 0; i < 32; ++i) {
        int p2 = h * 32 + ((i + c) & 31);
        float v = ldsx[c][p2];
        sx += v;
        sf = fmaf(v, sinv[p2], sf);
    }
    sx += __shfl_xor(sx, 1, 64);
    sf += __shfl_xor(sf, 1, 64);
    if (!(t & 1)) {
        atomicAdd(&meanbuf[(size_t)ab * 4096 + b * 128 + c], sx * (1.f / 1024.f));
        atomicAdd(&meanbuf[8192 + (size_t)ab * 4096 + b * 128 + c], sf * (1.f / 1024.f));
    }
}

// ---- conv1, m97-style: 128x128 tile, LDS dbuf, global_load_lds staging ----
// grid 256: ab(1) x b(32) x Mt(2) x Nt(2); 256 thr = 4 waves (2wm x 2wn), wave 64x64
__global__ __launch_bounds__(256) void k_conv1g(const u16* __restrict__ XC,
                                                const u16* __restrict__ A1p,
                                                u16* __restrict__ CC) {
    __shared__ u16 sA[2][4096];
    __shared__ u16 sB[2][4096];
    int t = threadIdx.x, l = t & 63;
    int wid = t >> 6, wm = wid & 1, wn = wid >> 1;
    int gid = blockIdx.x;
    int ab = gid >> 7, r = gid & 127, b = r >> 2, Mt = (r >> 1) & 1, Nt = r & 1;
    const u16* xc = XC + (size_t)ab * XSZ + (size_t)b * XBS;
    const u16* Ag = A1p + (size_t)Mt * (36 * 4096);

    auto stage = [&](int buf, int kc) {
        int tap = kc >> 2, q = kc & 3;
        int ky = tap / 3, kx = tap - ky * 3;
        const u16* ga = Ag + (size_t)kc * 4096 + t * 8;
        u16* da = &sA[buf][(t >> 6) * 512];
        gll16(ga, da);
        gll16(ga + 2048, da + 2048);
#pragma unroll
        for (int cph = 0; cph < 2; ++cph) {
            int idx = t + 256 * cph;
            int n = idx >> 2, s4 = idx & 3;
            int k8 = s4 ^ (n & 3);
            int row = Nt * 8 + (n >> 4), col = n & 15;
            int cc = q * 4 + k8;
            int pos = (2 * row + ky) * 34 + 2 * col + kx;
            gll16(xc + ((size_t)cc * 1156 + pos) * 8, &sB[buf][cph * 2048 + (t >> 6) * 512]);
        }
    };

    f4 acc[4][4] = {};
    stage(0, 0);
    int swz = ((l >> 4) ^ (l & 3)) * 8;
    for (int kc = 0; kc < 36; ++kc) {
        int cur = kc & 1;
        __syncthreads();
        if (kc + 1 < 36) stage(cur ^ 1, kc + 1);
        bf8 af[4], bfr[4];
        const u16* As = sA[cur];
        const u16* Bs = sB[cur];
#pragma unroll
        for (int mf = 0; mf < 4; ++mf)
            af[mf] = *(const bf8*)(As + (wm * 64 + mf * 16 + (l & 15)) * 32 + swz);
#pragma unroll
        for (int nf = 0; nf < 4; ++nf)
            bfr[nf] = *(const bf8*)(Bs + (wn * 64 + nf * 16 + (l & 15)) * 32 + swz);
#pragma unroll
        for (int mf = 0; mf < 4; ++mf)
#pragma unroll
            for (int nf = 0; nf < 4; ++nf)
                acc[mf][nf] = __builtin_amdgcn_mfma_f32_16x16x32_bf16(af[mf], bfr[nf], acc[mf][nf], 0, 0, 0);
    }
    u16* cb = CC + (size_t)ab * CSZ + (size_t)b * CBS;
#pragma unroll
    for (int mf = 0; mf < 4; ++mf) {
        int m = Mt * 128 + wm * 64 + mf * 16 + (l >> 4) * 4;
#pragma unroll
        for (int nf = 0; nf < 4; ++nf) {
            int nl = wn * 64 + nf * 16 + (l & 15);
            int oh = Nt * 8 + (nl >> 4), ow = nl & 15;
            int posO = (1 + oh) * 18 + 1 + ow;
            us4 pk;
#pragma unroll
            for (int r2 = 0; r2 < 4; ++r2) pk.v[r2] = f2bf(fmaxf(acc[mf][nf][r2], 0.f));
            *(us4*)(cb + ((size_t)(m >> 3) * 324 + posO) * 8 + (m & 7)) = pk;
        }
    }
}

// ---- conv2 (type0: relu+mean->feats) + deconv (type1: parity phases + MSE) ----
// grid 256: type(2) x ab(2) x b(32) x Nt(2); 256 thr, tile M128 x N128
__global__ __launch_bounds__(256) void k_cde2(const u16* __restrict__ CC,
                                              const u16* __restrict__ A2p,
                                              const u16* __restrict__ A3p,
                                              const u16* __restrict__ XC,
                                              float* __restrict__ feats,
                                              float* __restrict__ pr) {
    __shared__ u16 sA[2][4096];
    __shared__ u16 sB[2][4096];
    __shared__ float lds4[4];
    int t = threadIdx.x, l = t & 63;
    int wid = t >> 6, wm = wid & 1, wn = wid >> 1;
    int gid = blockIdx.x;
    int type = gid >> 7, u = gid & 127;
    int ab = u >> 6, r = u & 63, b = r >> 1, Nt = r & 1;
    const u16* cbb = CC + (size_t)ab * CSZ + (size_t)b * CBS;
    const u16* xq = XC + (size_t)ab * XSZ + (size_t)b * XBS;
    const u16* Ag = type ? A3p : A2p;

    auto stage = [&](int buf, int kc) {
        int tapi = kc >> 3, q = kc & 7;
        int tap = type ? TAPD9[tapi] : tapi;
        int ky = tap / 3, kx = tap - ky * 3;
        int po;
        if (type == 0) po = ky * 18 + kx;
        else po = ((ky + 1) >> 1) * 18 + ((kx + 1) >> 1);
        const u16* ga = Ag + (size_t)kc * 4096 + t * 8;
        u16* da = &sA[buf][(t >> 6) * 512];
        gll16(ga, da);
        gll16(ga + 2048, da + 2048);
#pragma unroll
        for (int cph = 0; cph < 2; ++cph) {
            int idx = t + 256 * cph;
            int n = idx >> 2, s4 = idx & 3;
            int k8 = s4 ^ (n & 3);
            int row = Nt * 8 + (n >> 4), col = n & 15;
            int cc = q * 4 + k8;
            int pos = row * 18 + col + po;
            gll16(cbb + ((size_t)cc * 324 + pos) * 8, &sB[buf][cph * 2048 + (t >> 6) * 512]);
        }
    };

    f4 acc[4][4] = {};
    float ss = 0.f;
    stage(0, 0);
    int swz = ((l >> 4) ^ (l & 3)) * 8;
    for (int kc = 0; kc < 72; ++kc) {
        int cur = kc & 1;
        __syncthreads();
        if (kc + 1 < 72) stage(cur ^ 1, kc + 1);
        bf8 af[4], bfr[4];
        const u16* As = sA[cur];
        const u16* Bs = sB[cur];
#pragma unroll
        for (int mf = 0; mf < 4; ++mf)
            af[mf] = *(const bf8*)(As + (wm * 64 + mf * 16 + (l & 15)) * 32 + swz);
#pragma unroll
        for (int nf = 0; nf < 4; ++nf)
            bfr[nf] = *(const bf8*)(Bs + (wn * 64 + nf * 16 + (l & 15)) * 32 + swz);
#pragma unroll
        for (int mf = 0; mf < 4; ++mf)
#pragma unroll
            for (int nf = 0; nf < 4; ++nf)
                acc[mf][nf] = __builtin_amdgcn_mfma_f32_16x16x32_bf16(af[mf], bfr[nf], acc[mf][nf], 0, 0, 0);
        if (type == 1 && (kc == 31 || kc == 47 || kc == 63 || kc == 71)) {
            int par = (kc == 31) ? 0 : (kc == 47) ? 1 : (kc == 63) ? 2 : 3;
            int py = par >> 1, px = par & 1;
#pragma unroll
            for (int mf = 0; mf < 4; ++mf) {
                int mb = wm * 64 + mf * 16 + (l >> 4) * 4;
                const u16* xrow = xq + ((size_t)(mb >> 3) * 1156) * 8 + (mb & 7);
#pragma unroll
                for (int nf = 0; nf < 4; ++nf) {
                    int nl = wn * 64 + nf * 16 + (l & 15);
                    int oh = Nt * 8 + (nl >> 4), ow = nl & 15;
                    int Y = 2 * oh + py, X = 2 * ow + px;
                    us4 xv = *(const us4*)(xrow + (size_t)(Y * 34 + X) * 8);
#pragma unroll
                    for (int r2 = 0; r2 < 4; ++r2) {
                        float d = acc[mf][nf][r2] - bf2f(xv.v[r2]);
                        ss = fmaf(d, d, ss);
                    }
                    f4 z = {0.f, 0.f, 0.f, 0.f};
                    acc[mf][nf] = z;
                }
            }
        }
    }
    if (type == 0) {
        float* fo = feats + ((size_t)ab * B_ + b) * CI;
#pragma unroll
        for (int mf = 0; mf < 4; ++mf)
#pragma unroll
            for (int r2 = 0; r2 < 4; ++r2) {
                float v = 0.f;
#pragma unroll
                for (int nf = 0; nf < 4; ++nf) v += fmaxf(acc[mf][nf][r2], 0.f);
                v += __shfl_xor(v, 1, 64);
                v += __shfl_xor(v, 2, 64);
                v += __shfl_xor(v, 4, 64);
                v += __shfl_xor(v, 8, 64);
                if ((l & 15) == 0)
                    atomicAdd(fo + wm * 64 + mf * 16 + (l >> 4) * 4 + r2, v * (1.f / 256.f));
            }
    } else {
        ss = blockSum256(ss, lds4);
        if (t == 0) atomicAdd(pr + ab, ss);
    }
}

// ---- metric (k_mix fused in: sets 2/3 computed from meanbuf) ----
__global__ __launch_bounds__(128) void k_metric(const float* __restrict__ feats,
                                                const float* __restrict__ meanbuf,
                                                const float* __restrict__ PnT,
                                                const float* __restrict__ pn2,
                                                const int* __restrict__ la,
                                                const int* __restrict__ lb,
                                                float* __restrict__ mo) {
    __shared__ float lds2[2];
    __shared__ float xs[128];
    int blk = blockIdx.x;
    int t = threadIdx.x;
    int b = blk & 31;
    float xv;
    if (blk < 64) xv = feats[(size_t)blk * CI + t];
    else if (blk < 96) xv = LAMF * meanbuf[b * 128 + t] + ILAMF * meanbuf[12288 + b * 128 + t];
    else xv = LAMF * meanbuf[4096 + b * 128 + t] + ILAMF * meanbuf[8192 + b * 128 + t];
    float ssq = blockSum128(xv * xv, lds2);
    float sc = SCALEF / fmaxf(sqrtf(ssq), 1e-12f);
    float xn = xv * sc;
    xs[t] = xn;
    float xn2 = blockSum128(xn * xn, lds2);
    bool active = (t < NB);
    float Dk = 1e30f;
    if (active) {
        float dot = 0.f;
#pragma unroll 8
        for (int e = 0; e < CI; ++e) dot = fmaf(xs[e], PnT[e * NB + t], dot);
        Dk = xn2 + pn2[t] - 2.f * dot;
    }
    float z = active ? -Dk : -1e30f;
    float m = blockMax128(z, lds2);
    float e = active ? expf(z - m) : 0.f;
    float se = blockSum128(e, lds2);
    float lse = m + logf(se);
    if (t == 0) mo[blk * 3 + 0] = lse;
    int A = la[b], Bb = lb[b];
    if (t == A) mo[blk * 3 + 1] = Dk;
    if (t == Bb) mo[blk * 3 + 2] = Dk;
}

__global__ __launch_bounds__(128) void k_final(const float* __restrict__ pr,
                                               const float* __restrict__ mo,
                                               float* __restrict__ out) {
    __shared__ float mla[4], mlb[4];
    int t = threadIdx.x;
    const float* m = mo + t * 3;
    float ula = m[0] + m[1];
    float ulb = m[0] + m[2];
#pragma unroll
    for (int off = 16; off > 0; off >>= 1) {
        ula += __shfl_down(ula, off, 32);
        ulb += __shfl_down(ulb, off, 32);
    }
    if ((t & 31) == 0) { mla[t >> 5] = ula * (1.f / 32.f); mlb[t >> 5] = ulb * (1.f / 32.f); }
    __syncthreads();
    if (t == 0) {
        float lxa = pr[0] * (1.f / 4194304.f);
        float lxb = pr[1] * (1.f / 4194304.f);
        float lca = mla[0];
        float lcb = mlb[1];
        float lcma = LAMF * mla[2] + ILAMF * mlb[2];
        float lcmb = LAMF * mlb[3] + ILAMF * mla[3];
        out[0] = lxa + lxb + lca + lcb + lcma + lcmb;
        out[1] = lxa; out[2] = lxb; out[3] = lca; out[4] = lcb; out[5] = lcma; out[6] = lcmb;
    }
}

extern "C" void kernel_launch(void* const* d_in, const int* in_sizes, int n_in,
                              void* d_out, int out_size, void* d_ws, size_t ws_size,
                              hipStream_t stream) {
    const float* xa = (const float*)d_in[0];
    const float* xb = (const float*)d_in[1];
    const int* la = (const int*)d_in[2];
    const int* lb = (const int*)d_in[3];
    const float* P = (const float*)d_in[4];
    const float* We = (const float*)d_in[5];
    const float* Wf = (const float*)d_in[6];
    const float* Wd = (const float*)d_in[7];

    char* w = (char*)d_ws;
    const size_t XPAD_B = XSZ * 2 * sizeof(u16);     // 18,939,904
    const size_t CPAD_B = CSZ * 2 * sizeof(u16);     // 10,616,832
    const size_t AW_B = (size_t)294912 * 2;
    u16* xpad = (u16*)w;                 w += XPAD_B;
    u16* cpad = (u16*)w;                 w += CPAD_B;
    u16* A1p = (u16*)w;                  w += AW_B;
    u16* A2p = (u16*)w;                  w += AW_B;
    u16* A3p = (u16*)w;                  w += AW_B;
    float* PnT = (float*)w;              w += 12800 * 4;
    float* pn2 = (float*)w;              w += 128 * 4;
    float* feats = (float*)w;            w += 8192 * 4;    // [2 ab][32][128] (conv2 out)
    float* meanbuf = (float*)w;          w += 16384 * 4;   // [2 kind][2 ab][32][128]
    float* pr = (float*)w;               w += 16 * 4;
    float* mo = (float*)w;               w += 384 * 4;
    float* out = (float*)d_out;

    // zero feats + meanbuf + pr in one shot (contiguous)
    hipMemsetAsync(feats, 0, (8192 + 16384 + 16) * sizeof(float), stream);

    k_prep_w<<<1152, 256, 0, stream>>>(We, Wf, Wd, A1p, A2p, A3p);
    k_prox<<<NB, 128, 0, stream>>>(P, PnT, pn2);
    k_ring<<<dim3(32, 2), 256, 0, stream>>>(xpad, cpad);
    k_xpose<<<dim3(32, 16, 2), 256, 0, stream>>>(xa, xb, xpad, meanbuf);
    k_conv1g<<<256, 256, 0, stream>>>(xpad, A1p, cpad);
    k_cde2<<<256, 256, 0, stream>>>(cpad, A2p, A3p, xpad, feats, pr);
    k_metric<<<128, 128, 0, stream>>>(feats, meanbuf, PnT, pn2, la, lb, mo);
    k_final<<<1, 128, 0, stream>>>(pr, mo, out);
}

// Round 7
// 109.940 us; speedup vs baseline: 1.4768x; 1.4768x over previous
//
#include <hip/hip_runtime.h>
#include <hip/hip_bf16.h>

#define DEVI __device__ __forceinline__

constexpr int B_ = 32, CI = 128, CM = 256, H_ = 32, W_ = 32;
constexpr int S_ = 1024, NB = 100;
constexpr float LAMF = 0.7f, ILAMF = 0.3f, SCALEF = 3.0f;
// chunked channel-last activation layouts: [b][ch/8][pos][8ch]
constexpr size_t XSZ = (size_t)32 * 16 * 1156 * 8;   // per-ab xpad elems (34x34 pos)
constexpr size_t XBS = (size_t)16 * 1156 * 8;        // per-b stride
constexpr size_t CSZ = (size_t)32 * 32 * 324 * 8;    // per-ab cpad elems (18x18 pos)
constexpr size_t CBS = (size_t)32 * 324 * 8;

typedef short bf8 __attribute__((ext_vector_type(8)));
typedef float f4 __attribute__((ext_vector_type(4)));
typedef unsigned short u16;
typedef unsigned int u32;

struct alignas(8) us4 { u16 v[4]; };
struct alignas(16) us8 { u16 v[8]; };

// deconv tap order, parity-grouped: par0{0,2,6,8} par1{1,7} par2{3,5} par3{4}
__device__ __constant__ int TAPD9c[9] = {0, 2, 6, 8, 1, 7, 3, 5, 4};

DEVI u16 f2bf(float f) {
    unsigned u = __builtin_bit_cast(unsigned, f);
    u += 0x7FFFu + ((u >> 16) & 1u);
    return (u16)(u >> 16);
}
DEVI float bf2f(u16 h) {
    unsigned u = ((unsigned)h) << 16;
    return __builtin_bit_cast(float, u);
}

DEVI void gll16(const void* g, void* l) {
    __builtin_amdgcn_global_load_lds(
        (const __attribute__((address_space(1))) u32*)g,
        (__attribute__((address_space(3))) u32*)l, 16, 0, 0);
}

DEVI float waveSum(float v) {
#pragma unroll
    for (int off = 32; off > 0; off >>= 1) v += __shfl_down(v, off, 64);
    return v;
}
DEVI float blockSum256(float v, float* lds4) {
    v = waveSum(v);
    int wid = threadIdx.x >> 6, lane = threadIdx.x & 63;
    __syncthreads();
    if (lane == 0) lds4[wid] = v;
    __syncthreads();
    return lds4[0] + lds4[1] + lds4[2] + lds4[3];
}
DEVI float blockSum128(float v, float* lds2) {
    v = waveSum(v);
    int wid = threadIdx.x >> 6, lane = threadIdx.x & 63;
    __syncthreads();
    if (lane == 0) lds2[wid] = v;
    __syncthreads();
    return lds2[0] + lds2[1];
}
DEVI float blockMax128(float v, float* lds2) {
#pragma unroll
    for (int off = 32; off > 0; off >>= 1) v = fmaxf(v, __shfl_down(v, off, 64));
    int wid = threadIdx.x >> 6, lane = threadIdx.x & 63;
    __syncthreads();
    if (lane == 0) lds2[wid] = v;
    __syncthreads();
    return fmaxf(lds2[0], lds2[1]);
}

// ---- weight prep: staging-linear k-slot-major layouts ----
// A1p: [Mt2][kc36][s512][8e]  s -> (q=s>>7, m=s&127); oc=Mt*128+m, ch=(kc&3)*32+q*8+e, tap=kc>>2
// A2p/A3p: [kc72][s512][8e]   s -> (q,m); ch=(kc&7)*32+q*8+e, tap=kc>>3 (A3p via TAPD9c)
__global__ __launch_bounds__(256) void k_prep_w(const float* __restrict__ We,
                                                const float* __restrict__ Wf,
                                                const float* __restrict__ Wd,
                                                u16* __restrict__ A1p,
                                                u16* __restrict__ A2p,
                                                u16* __restrict__ A3p) {
    int i = blockIdx.x * 256 + threadIdx.x;  // 294912
    {
        int e = i & 7, s = (i >> 3) & 511, j = i >> 12;  // j 0..71
        int Mt = j / 36, kc = j - Mt * 36;
        int tap = kc >> 2, cq = kc & 3;
        int q = s >> 7, m = s & 127;
        int oc = Mt * 128 + m, ch = cq * 32 + q * 8 + e;
        A1p[i] = f2bf(We[((size_t)oc * CI + ch) * 9 + tap]);
    }
    {
        int e = i & 7, s = (i >> 3) & 511, kc = i >> 12;  // 0..71
        int tapi = kc >> 3, cq = kc & 7;
        int q = s >> 7, m = s & 127;
        int ch = cq * 32 + q * 8 + e;
        A2p[i] = f2bf(Wf[((size_t)m * CM + ch) * 9 + tapi]);
        A3p[i] = f2bf(Wd[((size_t)m * CM + ch) * 9 + TAPD9c[tapi]]);
    }
}

// ---- proxies ----
__global__ __launch_bounds__(128) void k_prox(const float* __restrict__ P,
                                              float* __restrict__ PnT,
                                              float* __restrict__ pn2) {
    __shared__ float lds2[2];
    int k = blockIdx.x, t = threadIdx.x;
    float v = P[k * CI + t];
    float ss = blockSum128(v * v, lds2);
    float sc = SCALEF / fmaxf(sqrtf(ss), 1e-12f);
    float pv = v * sc;
    PnT[t * NB + k] = pv;
    float s2 = blockSum128(pv * pv, lds2);
    if (t == 0) pn2[k] = s2;
}

// ---- zero the padding rings of xpad and cpad ----
__global__ __launch_bounds__(256) void k_ring(u16* __restrict__ xpad, u16* __restrict__ cpad) {
    int b = blockIdx.x, ab = blockIdx.y, t = threadIdx.x;
    u16* xp = xpad + (size_t)ab * XSZ + (size_t)b * XBS;
    u16* cp = cpad + (size_t)ab * CSZ + (size_t)b * CBS;
    us8 z = {};
    for (int i = t; i < 132 * 16; i += 256) {
        int cc = i / 132, rp = i - cc * 132;
        int pos;
        if (rp < 68) pos = (rp < 34) ? (32 * 34 + rp) : (33 * 34 + rp - 34);
        else { int r2 = rp - 68; pos = (r2 >> 1) * 34 + 32 + (r2 & 1); }
        *(us8*)(xp + ((size_t)cc * 1156 + pos) * 8) = z;
    }
    for (int i = t; i < 68 * 32; i += 256) {
        int cc = i / 68, rp = i - cc * 68;
        int pos;
        if (rp < 36) pos = (rp < 18) ? rp : (17 * 18 + rp - 18);
        else { int r2 = rp - 36; pos = (1 + (r2 >> 1)) * 18 + ((r2 & 1) ? 17 : 0); }
        *(us8*)(cp + ((size_t)cc * 324 + pos) * 8) = z;
    }
}

// ---- fused: x -> bf16 chunked xpad + invd (LDS-only) + meanx/meanfl ----
__global__ __launch_bounds__(256) void k_xpose(const float* __restrict__ xa,
                                               const float* __restrict__ xb,
                                               u16* __restrict__ xpad,
                                               float* __restrict__ meanbuf) {
    __shared__ float ldsx[128][64];   // 32KB
    __shared__ float sred[256];
    __shared__ float sinv[64];
    int b = blockIdx.x, yg = blockIdx.y, ab = blockIdx.z;
    int t = threadIdx.x;
    const float* x = (ab ? xb : xa) + (size_t)b * CI * S_ + yg * 64;
    int c4 = t >> 6, p = t & 63;
    for (int c0 = 0; c0 < 32; ++c0) {
        int c = c0 * 4 + c4;
        ldsx[c][p] = x[(size_t)c * S_ + p];
    }
    __syncthreads();
    int qc = t >> 6;
    int y = yg * 2 + (p >> 5), xcol = p & 31;
    u16* ox = xpad + (size_t)ab * XSZ + (size_t)b * XBS;
    float ss = 0.f;
#pragma unroll
    for (int c8 = 0; c8 < 4; ++c8) {
        int cb = qc * 32 + c8 * 8;
        int cc = cb >> 3;
        us8 pk;
#pragma unroll
        for (int j = 0; j < 8; ++j) {
            float v = ldsx[cb + j][p];
            ss = fmaf(v, v, ss);
            pk.v[j] = f2bf(v);
        }
        *(us8*)(ox + ((size_t)cc * 1156 + y * 34 + xcol) * 8) = pk;
    }
    sred[t] = ss;
    __syncthreads();
    if (t < 64) {
        float s = sred[t] + sred[t + 64] + sred[t + 128] + sred[t + 192];
        sinv[t] = 1.f / fmaxf(sqrtf(s), 1e-12f);
    }
    __syncthreads();
    int c = t >> 1, h = t & 1;
    float sx = 0.f, sf = 0.f;
    for (int i = 0; i < 32; ++i) {
        int p2 = h * 32 + ((i + c) & 31);
        float v = ldsx[c][p2];
        sx += v;
        sf = fmaf(v, sinv[p2], sf);
    }
    sx += __shfl_xor(sx, 1, 64);
    sf += __shfl_xor(sf, 1, 64);
    if (!(t & 1)) {
        atomicAdd(&meanbuf[(size_t)ab * 4096 + b * 128 + c], sx * (1.f / 1024.f));
        atomicAdd(&meanbuf[8192 + (size_t)ab * 4096 + b * 128 + c], sf * (1.f / 1024.f));
    }
}

// ---- conv1: LDS dbuf, tile M128 x N64, wave M64 x N32, 2 blocks/CU ----
// grid (4 Nt, 32 b, 4: Mt*2+ab)
__global__ __launch_bounds__(256, 2) void k_conv1g(const u16* __restrict__ XC,
                                                   const u16* __restrict__ A1p,
                                                   u16* __restrict__ CC) {
    __shared__ u16 sA[2][4096];   // [q4][m128][8] per buf (8KB)
    __shared__ u16 sB[2][2048];   // [q4][n64][8] per buf (4KB)
    int t = threadIdx.x, l = t & 63, l15 = l & 15, lq = l >> 4, w = t >> 6;
    int wm = w & 1, wn = w >> 1;
    int Nt = blockIdx.x, b = blockIdx.y;
    int ab = blockIdx.z & 1, Mt = blockIdx.z >> 1;
    const u16* xc = XC + (size_t)ab * XSZ + (size_t)b * XBS;
    const u16* Ag = A1p + (size_t)Mt * (36 * 4096);
    // staging source geometry (lane l = slot n, wave w = k-slot q)
    int bpos0 = (8 * Nt + 2 * (l >> 4)) * 34 + 2 * (l & 15);
    const int po1[9] = {0, 1, 2, 34, 35, 36, 68, 69, 70};

    auto stageA = [&](int buf, int kc) {
        const u16* ga = Ag + (size_t)kc * 4096 + t * 8;
        u16* da = &sA[buf][w * 512];
        gll16(ga, da);
        gll16(ga + 2048, da + 2048);
    };
    auto stageB = [&](int buf, int po, int cq) {
        int cc = cq * 4 + w;
        gll16(xc + ((size_t)cc * 1156 + bpos0 + po) * 8, &sB[buf][w * 512]);
    };

    f4 acc[4][2] = {};
    stageA(0, 0);
    stageB(0, 0, 0);
    int cur = 0;
#pragma unroll
    for (int ti = 0; ti < 9; ++ti) {
        const int po = po1[ti];
        const int poN = (ti < 8) ? po1[ti + 1] : 0;
#pragma unroll 1
        for (int q = 0; q < 4; ++q) {
            __syncthreads();                      // publishes buf cur
            int kc = ti * 4 + q;
            if (kc + 1 < 36) {
                stageA(cur ^ 1, kc + 1);
                stageB(cur ^ 1, (q + 1 < 4) ? po : poN, (q + 1 < 4) ? q + 1 : 0);
            }
            const u16* As = sA[cur];
            const u16* Bs = sB[cur];
            bf8 af[4], bv[2];
#pragma unroll
            for (int mf = 0; mf < 4; ++mf)
                af[mf] = *(const bf8*)(As + lq * 1024 + (wm * 64 + mf * 16 + l15) * 8);
#pragma unroll
            for (int nf = 0; nf < 2; ++nf)
                bv[nf] = *(const bf8*)(Bs + lq * 512 + (wn * 32 + nf * 16 + l15) * 8);
#pragma unroll
            for (int mf = 0; mf < 4; ++mf)
#pragma unroll
                for (int nf = 0; nf < 2; ++nf)
                    acc[mf][nf] = __builtin_amdgcn_mfma_f32_16x16x32_bf16(af[mf], bv[nf], acc[mf][nf], 0, 0, 0);
            cur ^= 1;
        }
    }
    u16* cb = CC + (size_t)ab * CSZ + (size_t)b * CBS;
#pragma unroll
    for (int mf = 0; mf < 4; ++mf) {
        int mc = Mt * 128 + wm * 64 + mf * 16 + lq * 4;
#pragma unroll
        for (int nf = 0; nf < 2; ++nf) {
            int nl = wn * 32 + nf * 16 + l15;
            int oh = Nt * 4 + (nl >> 4), ow = nl & 15;
            int posO = (1 + oh) * 18 + 1 + ow;
            us4 pk;
#pragma unroll
            for (int r = 0; r < 4; ++r) pk.v[r] = f2bf(fmaxf(acc[mf][nf][r], 0.f));
            *(us4*)(cb + ((size_t)(mc >> 3) * 324 + posO) * 8 + (mc & 7)) = pk;
        }
    }
}

// ---- conv2 (type0: relu+mean->feats) + deconv (type1: parity phases + MSE) ----
// grid (4 Nt, 32 b, 4: type*2+ab); tile M128 x N64, LDS dbuf, 2 blocks/CU
__global__ __launch_bounds__(256, 2) void k_cde3(const u16* __restrict__ CC,
                                                 const u16* __restrict__ A2p,
                                                 const u16* __restrict__ A3p,
                                                 const u16* __restrict__ XC,
                                                 float* __restrict__ feats,
                                                 float* __restrict__ pr) {
    __shared__ u16 sA[2][4096];
    __shared__ u16 sB[2][2048];
    __shared__ float lds4[4];
    int t = threadIdx.x, l = t & 63, l15 = l & 15, lq = l >> 4, w = t >> 6;
    int wm = w & 1, wn = w >> 1;
    int Nt = blockIdx.x, b = blockIdx.y;
    int ab = blockIdx.z & 1, type = blockIdx.z >> 1;
    const u16* cbb = CC + (size_t)ab * CSZ + (size_t)b * CBS;
    const u16* xq = XC + (size_t)ab * XSZ + (size_t)b * XBS;
    const u16* Ag = type ? A3p : A2p;
    int bpos0 = (4 * Nt + (l >> 4)) * 18 + (l & 15);
    const int po2[9] = {0, 1, 2, 18, 19, 20, 36, 37, 38};
    const int poD[9] = {0, 1, 18, 19, 1, 19, 18, 19, 19};

    auto stageA = [&](int buf, int kc) {
        const u16* ga = Ag + (size_t)kc * 4096 + t * 8;
        u16* da = &sA[buf][w * 512];
        gll16(ga, da);
        gll16(ga + 2048, da + 2048);
    };
    auto stageB = [&](int buf, int po, int cq) {
        int cc = cq * 4 + w;
        gll16(cbb + ((size_t)cc * 324 + bpos0 + po) * 8, &sB[buf][w * 512]);
    };

    float ss = 0.f;
    f4 acc[4][2] = {};
    stageA(0, 0);
    stageB(0, 0, 0);
    int cur = 0;
#pragma unroll
    for (int ti = 0; ti < 9; ++ti) {
        const int po = type ? poD[ti] : po2[ti];
        const int poN = (ti < 8) ? (type ? poD[ti + 1] : po2[ti + 1]) : 0;
#pragma unroll 1
        for (int q = 0; q < 8; ++q) {
            __syncthreads();
            int kc = ti * 8 + q;
            if (kc + 1 < 72) {
                stageA(cur ^ 1, kc + 1);
                stageB(cur ^ 1, (q + 1 < 8) ? po : poN, (q + 1 < 8) ? q + 1 : 0);
            }
            const u16* As = sA[cur];
            const u16* Bs = sB[cur];
            bf8 af[4], bv[2];
#pragma unroll
            for (int mf = 0; mf < 4; ++mf)
                af[mf] = *(const bf8*)(As + lq * 1024 + (wm * 64 + mf * 16 + l15) * 8);
#pragma unroll
            for (int nf = 0; nf < 2; ++nf)
                bv[nf] = *(const bf8*)(Bs + lq * 512 + (wn * 32 + nf * 16 + l15) * 8);
#pragma unroll
            for (int mf = 0; mf < 4; ++mf)
#pragma unroll
                for (int nf = 0; nf < 2; ++nf)
                    acc[mf][nf] = __builtin_amdgcn_mfma_f32_16x16x32_bf16(af[mf], bv[nf], acc[mf][nf], 0, 0, 0);
            cur ^= 1;
        }
        // deconv parity flush after taps {0,2,6,8}|{1,7}|{3,5}|{4}
        if (type && (ti == 3 || ti == 5 || ti == 7 || ti == 8)) {
            int par = (ti == 3) ? 0 : (ti == 5) ? 1 : (ti == 7) ? 2 : 3;
            int py = par >> 1, px = par & 1;
#pragma unroll
            for (int mf = 0; mf < 4; ++mf) {
                int mc = wm * 64 + mf * 16 + lq * 4;
                const u16* xrow = xq + (size_t)(mc >> 3) * 1156 * 8 + (mc & 7);
#pragma unroll
                for (int nf = 0; nf < 2; ++nf) {
                    int nl = wn * 32 + nf * 16 + l15;
                    int oh = Nt * 4 + (nl >> 4), ow = nl & 15;
                    int Y = 2 * oh + py, X = 2 * ow + px;
                    us4 xv = *(const us4*)(xrow + (size_t)(Y * 34 + X) * 8);
#pragma unroll
                    for (int r = 0; r < 4; ++r) {
                        float d = acc[mf][nf][r] - bf2f(xv.v[r]);
                        ss = fmaf(d, d, ss);
                    }
                    f4 z = {0.f, 0.f, 0.f, 0.f};
                    acc[mf][nf] = z;
                }
            }
        }
    }
    if (type == 0) {
        float* fo = feats + ((size_t)ab * B_ + b) * CI;
#pragma unroll
        for (int mf = 0; mf < 4; ++mf)
#pragma unroll
            for (int r = 0; r < 4; ++r) {
                float v = fmaxf(acc[mf][0][r], 0.f) + fmaxf(acc[mf][1][r], 0.f);
                v += __shfl_xor(v, 1, 64);
                v += __shfl_xor(v, 2, 64);
                v += __shfl_xor(v, 4, 64);
                v += __shfl_xor(v, 8, 64);
                if (l15 == 0)
                    atomicAdd(fo + wm * 64 + mf * 16 + lq * 4 + r, v * (1.f / 256.f));
            }
    } else {
        ss = blockSum256(ss, lds4);
        if (t == 0) atomicAdd(pr + ab, ss);
    }
}

// ---- metric (mix fused: sets 2/3 from meanbuf; Sinkhorn dead code) ----
__global__ __launch_bounds__(128) void k_metric(const float* __restrict__ feats,
                                                const float* __restrict__ meanbuf,
                                                const float* __restrict__ PnT,
                                                const float* __restrict__ pn2,
                                                const int* __restrict__ la,
                                                const int* __restrict__ lb,
                                                float* __restrict__ mo) {
    __shared__ float lds2[2];
    __shared__ float xs[128];
    int blk = blockIdx.x;
    int t = threadIdx.x;
    int b = blk & 31;
    float xv;
    if (blk < 64) xv = feats[(size_t)blk * CI + t];
    else if (blk < 96) xv = LAMF * meanbuf[b * 128 + t] + ILAMF * meanbuf[12288 + b * 128 + t];
    else xv = LAMF * meanbuf[4096 + b * 128 + t] + ILAMF * meanbuf[8192 + b * 128 + t];
    float ssq = blockSum128(xv * xv, lds2);
    float sc = SCALEF / fmaxf(sqrtf(ssq), 1e-12f);
    float xn = xv * sc;
    xs[t] = xn;
    float xn2 = blockSum128(xn * xn, lds2);
    bool active = (t < NB);
    float Dk = 1e30f;
    if (active) {
        float dot = 0.f;
#pragma unroll 8
        for (int e = 0; e < CI; ++e) dot = fmaf(xs[e], PnT[e * NB + t], dot);
        Dk = xn2 + pn2[t] - 2.f * dot;
    }
    float z = active ? -Dk : -1e30f;
    float m = blockMax128(z, lds2);
    float e = active ? expf(z - m) : 0.f;
    float se = blockSum128(e, lds2);
    float lse = m + logf(se);
    if (t == 0) mo[blk * 3 + 0] = lse;
    int A = la[b], Bb = lb[b];
    if (t == A) mo[blk * 3 + 1] = Dk;
    if (t == Bb) mo[blk * 3 + 2] = Dk;
}

__global__ __launch_bounds__(128) void k_final(const float* __restrict__ pr,
                                               const float* __restrict__ mo,
                                               float* __restrict__ out) {
    __shared__ float mla[4], mlb[4];
    int t = threadIdx.x;
    const float* m = mo + t * 3;
    float ula = m[0] + m[1];
    float ulb = m[0] + m[2];
#pragma unroll
    for (int off = 16; off > 0; off >>= 1) {
        ula += __shfl_down(ula, off, 32);
        ulb += __shfl_down(ulb, off, 32);
    }
    if ((t & 31) == 0) { mla[t >> 5] = ula * (1.f / 32.f); mlb[t >> 5] = ulb * (1.f / 32.f); }
    __syncthreads();
    if (t == 0) {
        float lxa = pr[0] * (1.f / 4194304.f);
        float lxb = pr[1] * (1.f / 4194304.f);
        float lca = mla[0];
        float lcb = mlb[1];
        float lcma = LAMF * mla[2] + ILAMF * mlb[2];
        float lcmb = LAMF * mlb[3] + ILAMF * mla[3];
        out[0] = lxa + lxb + lca + lcb + lcma + lcmb;
        out[1] = lxa; out[2] = lxb; out[3] = lca; out[4] = lcb; out[5] = lcma; out[6] = lcmb;
    }
}

extern "C" void kernel_launch(void* const* d_in, const int* in_sizes, int n_in,
                              void* d_out, int out_size, void* d_ws, size_t ws_size,
                              hipStream_t stream) {
    const float* xa = (const float*)d_in[0];
    const float* xb = (const float*)d_in[1];
    const int* la = (const int*)d_in[2];
    const int* lb = (const int*)d_in[3];
    const float* P = (const float*)d_in[4];
    const float* We = (const float*)d_in[5];
    const float* Wf = (const float*)d_in[6];
    const float* Wd = (const float*)d_in[7];

    char* w = (char*)d_ws;
    const size_t XPAD_B = XSZ * 2 * sizeof(u16);
    const size_t CPAD_B = CSZ * 2 * sizeof(u16);
    const size_t AW_B = (size_t)294912 * 2;
    u16* xpad = (u16*)w;                 w += XPAD_B;
    u16* cpad = (u16*)w;                 w += CPAD_B;
    u16* A1p = (u16*)w;                  w += AW_B;
    u16* A2p = (u16*)w;                  w += AW_B;
    u16* A3p = (u16*)w;                  w += AW_B;
    float* PnT = (float*)w;              w += 12800 * 4;
    float* pn2 = (float*)w;              w += 128 * 4;
    float* feats = (float*)w;            w += 8192 * 4;    // [2 ab][32][128]
    float* meanbuf = (float*)w;          w += 16384 * 4;   // [2 kind][2 ab][32][128]
    float* pr = (float*)w;               w += 16 * 4;
    float* mo = (float*)w;               w += 384 * 4;
    float* out = (float*)d_out;

    hipMemsetAsync(feats, 0, (8192 + 16384 + 16) * sizeof(float), stream);

    k_prep_w<<<1152, 256, 0, stream>>>(We, Wf, Wd, A1p, A2p, A3p);
    k_prox<<<NB, 128, 0, stream>>>(P, PnT, pn2);
    k_ring<<<dim3(32, 2), 256, 0, stream>>>(xpad, cpad);
    k_xpose<<<dim3(32, 16, 2), 256, 0, stream>>>(xa, xb, xpad, meanbuf);
    k_conv1g<<<dim3(4, 32, 4), 256, 0, stream>>>(xpad, A1p, cpad);
    k_cde3<<<dim3(4, 32, 4), 256, 0, stream>>>(cpad, A2p, A3p, xpad, feats, pr);
    k_metric<<<128, 128, 0, stream>>>(feats, meanbuf, PnT, pn2, la, lb, mo);
    k_final<<<1, 128, 0, stream>>>(pr, mo, out);
}